// Round 8
// baseline (306.125 us; speedup 1.0000x reference)
//
#include <hip/hip_runtime.h>

// Problem constants
#define BATCH 4
#define COUT  256
#define HW    4096      // 64*64
#define DGRP  4         // deformable groups
#define CG    64        // channels per deformable group
#define KK    9         // 3x3 taps
#define NCH   36        // DGRP*KK chunks of 64 input-channels
#define KTOT  2304      // DGRP*KK*CG
#define NKSTEP 72       // KTOT/32 mfma K-steps
#define GNUM  32        // GroupNorm groups
#define GN_N  32768.0f  // elements per GN group
#define TP    32        // pixels per tile (BM)

// ws layout (float offsets)
#define OFF_COEFF 0
#define SZ_COEFF  (BATCH*NCH*HW*4)          // [b][dgkk][pix] float4
#define OFF_WB    (OFF_COEFF + SZ_COEFF)    // bf16 wB[72][256][32] (as ushort)
#define SZ_WB     (KTOT*COUT/2)             // 294,912 floats
#define OFF_Y     (OFF_WB + SZ_WB)
#define SZ_Y      (BATCH*COUT*HW)
#define OFF_GSUM  (OFF_Y + SZ_Y)
#define OFF_GSQ   (OFF_GSUM + 128)
#define OFF_MEAN  (OFF_GSQ + 128)
#define OFF_RSTD  (OFF_MEAN + 128)

typedef __attribute__((ext_vector_type(8))) short short8;
typedef __attribute__((ext_vector_type(4))) float f32x4;

__device__ __forceinline__ ushort f2bf(float f) {
    unsigned u = __float_as_uint(f);
    unsigned r = (u + 0x7FFFu + ((u >> 16) & 1u)) >> 16;   // RNE
    return (ushort)r;
}

// ---------------------------------------------------------------------------
// Kernel 1: bilinear coefficients, layout [b][dgkk][pix] (coalesced in pix).
// coeff = float4{ y0(int bits), x0(int bits), wy1, wx1 }   [verified r4]
__global__ void offs_kernel(const float* __restrict__ shp,
                            const float* __restrict__ wo,
                            float4* __restrict__ coeff) {
    int tid = blockIdx.x * 256 + threadIdx.x;
    if (tid >= BATCH * NCH * HW) return;
    int pix  = tid & (HW - 1);
    int rest = tid >> 12;
    int dgkk = rest % NCH;
    int b    = rest / NCH;
    int kk   = dgkk % KK;

    float s0 = shp[(b*4 + 0)*HW + pix];
    float s1 = shp[(b*4 + 1)*HW + pix];
    float s2 = shp[(b*4 + 2)*HW + pix];
    float s3 = shp[(b*4 + 3)*HW + pix];
    const float* w0 = wo + (dgkk * 2) * 4;     // dy row
    const float* w1 = w0 + 4;                  // dx row
    float offy = s0*w0[0] + s1*w0[1] + s2*w0[2] + s3*w0[3];
    float offx = s0*w1[0] + s1*w1[1] + s2*w1[2] + s3*w1[3];

    int h = pix >> 6, w = pix & 63;
    float py = (float)(h + kk/3 - 1) + offy;
    float px = (float)(w + kk%3 - 1) + offx;
    float y0f = floorf(py), x0f = floorf(px);
    float4 o;
    o.x = __int_as_float((int)y0f);
    o.y = __int_as_float((int)x0f);
    o.z = py - y0f;
    o.w = px - x0f;
    coeff[tid] = o;   // tid == (b*NCH+dgkk)*HW + pix
}

// ---------------------------------------------------------------------------
// Kernel 2: pack deform weight to bf16 wB[kstep][out][k32]   [verified r4]
__global__ void wb_kernel(const float* __restrict__ wd, ushort* __restrict__ wB) {
    int tid = blockIdx.x * 256 + threadIdx.x;
    if (tid >= NKSTEP * COUT * 32) return;
    int k32   = tid & 31;
    int out   = (tid >> 5) & 255;
    int kstep = tid >> 13;
    int k    = kstep * 32 + k32;
    int dgkk = k >> 6;
    int c    = k & 63;
    int dg = dgkk / KK, kk = dgkk % KK;
    wB[tid] = f2bf(wd[out * KTOT + (dg * CG + c) * KK + kk]);
}

// ---------------------------------------------------------------------------
// Kernel 3: fused bilinear-sample + bf16-MFMA implicit GEMM + GN partials.
// DELTA vs verified round-4 kernel: out-channel dimension split across 2
// blocks (h = blockIdx.x&1 owns outs h*128..h*128+127), grid 512->1024,
// launch_bounds (256,2)->(256,4). Blocks (2i,2i+1) share pixel tile i
// (sampling duplicated; gathers L2-resident). All sampling / LDS layout /
// fragment math is byte-identical to the passing round-4 version.
__launch_bounds__(256, 4)
__global__ void main_kernel(const float* __restrict__ x,
                            const float4* __restrict__ coeff,
                            const ushort* __restrict__ wB,
                            float* __restrict__ y,
                            float* __restrict__ gsum,
                            float* __restrict__ gsq) {
    __shared__ ushort Sm[2][TP * 64];      // [pix][c] bf16, XOR-swizzled 16B slots
    __shared__ float lsum[GNUM], lsq[GNUM];

    const int tid   = threadIdx.x;
    const int lane  = tid & 63;
    const int wv    = tid >> 6;                 // wave id 0..3
    const int tile  = (int)blockIdx.x >> 1;     // pixel tile 0..511
    const int hhalf = (int)blockIdx.x & 1;      // out-channel half 0..1
    const int b     = tile >> 7;                // 128 tiles per batch
    const int pix0  = (tile & 127) << 5;
    const int pixs  = tid & 31;                 // sampling-phase pixel
    const int cslot = tid >> 5;                 // sampling-phase 8-channel slot

    if (tid < GNUM) { lsum[tid] = 0.f; lsq[tid] = 0.f; }

    f32x4 acc[2][2];                            // [nt][mt]
#pragma unroll
    for (int i = 0; i < 2; ++i)
#pragma unroll
        for (int j = 0; j < 2; ++j) acc[i][j] = (f32x4)0.f;

    float lv[4][8];   // [tap][ch j] raw gathers for next chunk
    float wgt[4];     // bilinear weights for next chunk

    auto sample_load = [&](int ch) {
        float4 cf = coeff[(size_t)(b * NCH + ch) * HW + pix0 + pixs];
        int y0 = __float_as_int(cf.x), x0 = __float_as_int(cf.y);
        float wy1 = cf.z, wx1 = cf.w;
        float wy0 = 1.f - wy1, wx0 = 1.f - wx1;
        int y1 = y0 + 1, x1 = x0 + 1;
        bool vy0 = (unsigned)y0 < 64u, vy1 = (unsigned)y1 < 64u;
        bool vx0 = (unsigned)x0 < 64u, vx1 = (unsigned)x1 < 64u;
        int cy0 = min(max(y0, 0), 63), cy1 = min(max(y1, 0), 63);
        int cx0 = min(max(x0, 0), 63), cx1 = min(max(x1, 0), 63);
        wgt[0] = (vy0 && vx0) ? wy0 * wx0 : 0.f;
        wgt[1] = (vy0 && vx1) ? wy0 * wx1 : 0.f;
        wgt[2] = (vy1 && vx0) ? wy1 * wx0 : 0.f;
        wgt[3] = (vy1 && vx1) ? wy1 * wx1 : 0.f;
        int i00 = cy0 * 64 + cx0, i01 = cy0 * 64 + cx1;
        int i10 = cy1 * 64 + cx0, i11 = cy1 * 64 + cx1;
        int dg = ch / KK;
        const float* xp = x + (size_t)((b * DGRP + dg) * CG + cslot * 8) * HW;
#pragma unroll
        for (int j = 0; j < 8; ++j) {
            lv[0][j] = xp[i00];
            lv[1][j] = xp[i01];
            lv[2][j] = xp[i10];
            lv[3][j] = xp[i11];
            xp += HW;
        }
    };
    auto sample_store = [&](int buf) {
        short8 frag;
#pragma unroll
        for (int j = 0; j < 8; ++j) {
            float v = wgt[0]*lv[0][j] + wgt[1]*lv[1][j]
                    + wgt[2]*lv[2][j] + wgt[3]*lv[3][j];
            frag[j] = (short)f2bf(v);
        }
        int swslot = cslot ^ (pixs & 7);        // T2 XOR swizzle, 16B slots
        *reinterpret_cast<short8*>(&Sm[buf][pixs * 64 + swslot * 8]) = frag;
    };

    // prologue: chunk 0
    sample_load(0);
    sample_store(0);
    __syncthreads();

    for (int ch = 0; ch < NCH; ++ch) {
        if (ch + 1 < NCH) sample_load(ch + 1);   // gathers in flight during GEMM

        const ushort* Sb = Sm[ch & 1];
#pragma unroll
        for (int ss = 0; ss < 2; ++ss) {
            const int kstep = ch * 2 + ss;
            // A-frags: pix = mt*16 + (lane&15), k8-block = lane>>4
            short8 afrag[2];
#pragma unroll
            for (int mt = 0; mt < 2; ++mt) {
                int pix  = mt * 16 + (lane & 15);
                int slot = (ss * 4 + (lane >> 4)) ^ (pix & 7);
                afrag[mt] = *reinterpret_cast<const short8*>(&Sb[pix * 64 + slot * 8]);
            }
#pragma unroll
            for (int nt = 0; nt < 2; ++nt) {
                int out = hhalf * 128 + wv * 32 + nt * 16 + (lane & 15);
                const short8* bp = reinterpret_cast<const short8*>(
                    wB + ((size_t)(kstep * 256 + out) * 32 + (lane >> 4) * 8));
                short8 bfrag = *bp;
#pragma unroll
                for (int mt = 0; mt < 2; ++mt)
                    acc[nt][mt] = __builtin_amdgcn_mfma_f32_16x16x32_bf16(
                        afrag[mt], bfrag, acc[nt][mt], 0, 0, 0);
            }
        }

        if (ch + 1 < NCH) sample_store((ch + 1) & 1);
        __syncthreads();
    }

    // ---- epilogue: write y, accumulate GN stats ----
#pragma unroll
    for (int nt = 0; nt < 2; ++nt) {
        int out = hhalf * 128 + wv * 32 + nt * 16 + (lane & 15);
        float s_ = 0.f, q_ = 0.f;
#pragma unroll
        for (int mt = 0; mt < 2; ++mt) {
            float4 st;
            st.x = acc[nt][mt][0]; st.y = acc[nt][mt][1];
            st.z = acc[nt][mt][2]; st.w = acc[nt][mt][3];
            s_ += st.x + st.y + st.z + st.w;
            q_ += st.x*st.x + st.y*st.y + st.z*st.z + st.w*st.w;
            float* yr = y + (size_t)(b * COUT + out) * HW
                          + pix0 + mt * 16 + (lane >> 4) * 4;
            *reinterpret_cast<float4*>(yr) = st;
        }
        atomicAdd(&lsum[out >> 3], s_);
        atomicAdd(&lsq [out >> 3], q_);
    }
    __syncthreads();
    if (tid < GNUM) {
        float ls = lsum[tid], lq = lsq[tid];
        if (ls != 0.f || lq != 0.f) {           // this block touched group tid?
            atomicAdd(&gsum[b * GNUM + tid], ls);
            atomicAdd(&gsq [b * GNUM + tid], lq);
        }
    }
}

// ---------------------------------------------------------------------------
// Kernel 4: finalize GN statistics (128 groups)
__global__ void stats_kernel(const float* __restrict__ gsum,
                             const float* __restrict__ gsq,
                             float* __restrict__ mean,
                             float* __restrict__ rstd) {
    int t = threadIdx.x;
    if (t < BATCH * GNUM) {
        float m = gsum[t] * (1.f / GN_N);
        float v = gsq[t] * (1.f / GN_N) - m * m;
        mean[t] = m;
        rstd[t] = rsqrtf(v + 1e-5f);
    }
}

// ---------------------------------------------------------------------------
// Kernel 5: apply GN affine + ReLU (float4, memory-bound)
__global__ void apply_kernel(const float* __restrict__ y,
                             const float* __restrict__ mean,
                             const float* __restrict__ rstd,
                             const float* __restrict__ gamma,
                             const float* __restrict__ beta,
                             float* __restrict__ out) {
    int i = blockIdx.x * 256 + threadIdx.x;        // float4 index
    if (i >= (BATCH * COUT * HW) / 4) return;
    float4 v = ((const float4*)y)[i];
    int idx = i * 4;
    int b = idx >> 20;
    int c = (idx >> 12) & 255;
    int gi = b * GNUM + (c >> 3);
    float r = rstd[gi];
    float g = gamma[c] * r;
    float be = beta[c] - mean[gi] * g;
    float4 o;
    o.x = fmaxf(v.x * g + be, 0.f);
    o.y = fmaxf(v.y * g + be, 0.f);
    o.z = fmaxf(v.z * g + be, 0.f);
    o.w = fmaxf(v.w * g + be, 0.f);
    ((float4*)out)[i] = o;
}

// ---------------------------------------------------------------------------
extern "C" void kernel_launch(void* const* d_in, const int* in_sizes, int n_in,
                              void* d_out, int out_size, void* d_ws, size_t ws_size,
                              hipStream_t stream) {
    const float* x     = (const float*)d_in[0];
    const float* shp   = (const float*)d_in[1];
    const float* wo    = (const float*)d_in[2];
    const float* wd    = (const float*)d_in[3];
    const float* gamma = (const float*)d_in[4];
    const float* beta  = (const float*)d_in[5];
    float* out = (float*)d_out;
    float* ws  = (float*)d_ws;

    float4* coeff = (float4*)(ws + OFF_COEFF);
    ushort* wB    = (ushort*)(ws + OFF_WB);
    float*  y     = ws + OFF_Y;
    float*  gsum  = ws + OFF_GSUM;
    float*  gsq   = ws + OFF_GSQ;
    float*  mean  = ws + OFF_MEAN;
    float*  rstd  = ws + OFF_RSTD;

    // zero GN accumulators (gsum+gsq contiguous, 256 floats)
    hipMemsetAsync(gsum, 0, 256 * sizeof(float), stream);

    offs_kernel<<<dim3((BATCH*NCH*HW + 255) / 256), dim3(256), 0, stream>>>(shp, wo, coeff);
    wb_kernel<<<dim3((NKSTEP*COUT*32 + 255) / 256), dim3(256), 0, stream>>>(wd, wB);
    main_kernel<<<dim3(1024), dim3(256), 0, stream>>>(x, coeff, wB, y, gsum, gsq);
    stats_kernel<<<dim3(1), dim3(128), 0, stream>>>(gsum, gsq, mean, rstd);
    apply_kernel<<<dim3((BATCH*COUT*HW/4 + 255) / 256), dim3(256), 0, stream>>>(
        y, mean, rstd, gamma, beta, out);
}

// Round 9
// 207.597 us; speedup vs baseline: 1.4746x; 1.4746x over previous
//
#include <hip/hip_runtime.h>

// Problem constants
#define BATCH 4
#define COUT  256
#define HW    4096      // 64*64
#define DGRP  4         // deformable groups
#define CG    64        // channels per deformable group
#define KK    9         // 3x3 taps
#define NCH   36        // DGRP*KK chunks of 64 input-channels
#define KTOT  2304      // DGRP*KK*CG
#define NKSTEP 72       // KTOT/32 mfma K-steps
#define GNUM  32        // GroupNorm groups
#define GN_N  32768.0f  // elements per GN group

// ws layout (float offsets)
#define OFF_COEFF 0
#define SZ_COEFF  (BATCH*NCH*HW*4)          // [b][dgkk][pix] float4      (9.4 MB)
#define OFF_WB    (OFF_COEFF + SZ_COEFF)    // bf16 wB[72][256][32]       (1.2 MB)
#define SZ_WB     (KTOT*COUT/2)
#define OFF_S     (OFF_WB + SZ_WB)          // bf16 S[b][dgkk][pix][64]   (75.5 MB)
#define SZ_S      (BATCH*NCH*HW*64/2)       // 9,437,184 floats
#define OFF_Y     (OFF_S + SZ_S)            // fp32 y[b][out][pix]        (16.8 MB)
#define SZ_Y      (BATCH*COUT*HW)
#define OFF_GSUM  (OFF_Y + SZ_Y)
#define OFF_GSQ   (OFF_GSUM + 128)
#define OFF_MEAN  (OFF_GSQ + 128)
#define OFF_RSTD  (OFF_MEAN + 128)

typedef __attribute__((ext_vector_type(8))) short short8;
typedef __attribute__((ext_vector_type(4))) float f32x4;

__device__ __forceinline__ ushort f2bf(float f) {
    unsigned u = __float_as_uint(f);
    unsigned r = (u + 0x7FFFu + ((u >> 16) & 1u)) >> 16;   // RNE
    return (ushort)r;
}

// ---------------------------------------------------------------------------
// Kernel 1: bilinear coefficients, layout [b][dgkk][pix].   [verified r4/r8]
__global__ void offs_kernel(const float* __restrict__ shp,
                            const float* __restrict__ wo,
                            float4* __restrict__ coeff) {
    int tid = blockIdx.x * 256 + threadIdx.x;
    if (tid >= BATCH * NCH * HW) return;
    int pix  = tid & (HW - 1);
    int rest = tid >> 12;
    int dgkk = rest % NCH;
    int b    = rest / NCH;
    int kk   = dgkk % KK;

    float s0 = shp[(b*4 + 0)*HW + pix];
    float s1 = shp[(b*4 + 1)*HW + pix];
    float s2 = shp[(b*4 + 2)*HW + pix];
    float s3 = shp[(b*4 + 3)*HW + pix];
    const float* w0 = wo + (dgkk * 2) * 4;     // dy row
    const float* w1 = w0 + 4;                  // dx row
    float offy = s0*w0[0] + s1*w0[1] + s2*w0[2] + s3*w0[3];
    float offx = s0*w1[0] + s1*w1[1] + s2*w1[2] + s3*w1[3];

    int h = pix >> 6, w = pix & 63;
    float py = (float)(h + kk/3 - 1) + offy;
    float px = (float)(w + kk%3 - 1) + offx;
    float y0f = floorf(py), x0f = floorf(px);
    float4 o;
    o.x = __int_as_float((int)y0f);
    o.y = __int_as_float((int)x0f);
    o.z = py - y0f;
    o.w = px - x0f;
    coeff[tid] = o;   // tid == (b*NCH+dgkk)*HW + pix
}

// ---------------------------------------------------------------------------
// Kernel 2: pack deform weight to bf16 wB[kstep][out][k32]   [verified r4/r8]
__global__ void wb_kernel(const float* __restrict__ wd, ushort* __restrict__ wB) {
    int tid = blockIdx.x * 256 + threadIdx.x;
    if (tid >= NKSTEP * COUT * 32) return;
    int k32   = tid & 31;
    int out   = (tid >> 5) & 255;
    int kstep = tid >> 13;
    int k    = kstep * 32 + k32;
    int dgkk = k >> 6;
    int c    = k & 63;
    int dg = dgkk / KK, kk = dgkk % KK;
    wB[tid] = f2bf(wd[out * KTOT + (dg * CG + c) * KK + kk]);
}

// ---------------------------------------------------------------------------
// Kernel 3: bilinear sampling -> global S[b][dgkk][pix][64ch] (bf16,
// slot-XOR-swizzled exactly like the verified r4 LDS layout).
// Barrier-free, full occupancy: block = (b, dgkk, 32-pixel tile);
// thread = (pixel, 8-channel slot). Sampling math byte-identical to r4.
__launch_bounds__(256)
__global__ void sample_kernel(const float* __restrict__ x,
                              const float4* __restrict__ coeff,
                              ushort* __restrict__ Sg) {
    // XCD-chunked bijective swizzle (18432 = 8 * 2304)
    int bid  = ((int)blockIdx.x & 7) * 2304 + ((int)blockIdx.x >> 3);
    int tile = bid & 127;
    int rest = bid >> 7;           // 0..143
    int dgkk = rest % NCH;
    int b    = rest / NCH;
    const int pix0  = tile << 5;
    const int tid   = threadIdx.x;
    const int pixs  = tid & 31;
    const int cslot = tid >> 5;    // 8-channel slot 0..7
    const int dg    = dgkk / KK;

    float4 cf = coeff[(size_t)(b * NCH + dgkk) * HW + pix0 + pixs];
    int y0 = __float_as_int(cf.x), x0 = __float_as_int(cf.y);
    float wy1 = cf.z, wx1 = cf.w;
    float wy0 = 1.f - wy1, wx0 = 1.f - wx1;
    int y1 = y0 + 1, x1 = x0 + 1;
    bool vy0 = (unsigned)y0 < 64u, vy1 = (unsigned)y1 < 64u;
    bool vx0 = (unsigned)x0 < 64u, vx1 = (unsigned)x1 < 64u;
    int cy0 = min(max(y0, 0), 63), cy1 = min(max(y1, 0), 63);
    int cx0 = min(max(x0, 0), 63), cx1 = min(max(x1, 0), 63);
    float w00 = (vy0 && vx0) ? wy0 * wx0 : 0.f;
    float w01 = (vy0 && vx1) ? wy0 * wx1 : 0.f;
    float w10 = (vy1 && vx0) ? wy1 * wx0 : 0.f;
    float w11 = (vy1 && vx1) ? wy1 * wx1 : 0.f;
    int i00 = cy0 * 64 + cx0, i01 = cy0 * 64 + cx1;
    int i10 = cy1 * 64 + cx0, i11 = cy1 * 64 + cx1;

    const float* xp = x + (size_t)((b * DGRP + dg) * CG + cslot * 8) * HW;
    short8 frag;
#pragma unroll
    for (int j = 0; j < 8; ++j) {
        float v = w00 * xp[i00] + w01 * xp[i01]
                + w10 * xp[i10] + w11 * xp[i11];
        frag[j] = (short)f2bf(v);
        xp += HW;
    }
    int swslot = cslot ^ (pixs & 7);        // T2 XOR swizzle, 16B slots (r4)
    *reinterpret_cast<short8*>(
        &Sg[((size_t)(b * NCH + dgkk) * HW + pix0 + pixs) * 64 + swslot * 8]) = frag;
}

// ---------------------------------------------------------------------------
// Kernel 4: dense bf16-MFMA GEMM  y[b][out][pix] = sum_k S[b][k][pix]*wB.
// Grid: 1024 blocks (b x 64 pix-tiles x 4 out-quarters), XCD-swizzled.
// Block: 256 thr (4 waves) = 64pix x 64out tile; wave wv owns outs
// q*64+wv*16..+15, acc[mt=4] over 64 pixels. K-loop: 36 chunks of 64;
// A staged LDS double-buffered (reg-staged; B-loads issued FIRST so MFMA
// waits only on them; stage writes drain under the GEMM - T14).
// Fragment geometry identical to verified r4 kernel.
__launch_bounds__(256, 4)
__global__ void gemm_kernel(const ushort* __restrict__ Sg,
                            const ushort* __restrict__ wB,
                            float* __restrict__ y,
                            float* __restrict__ gsum,
                            float* __restrict__ gsq) {
    __shared__ ushort Sm[2][64 * 64];      // [pixL][64k] swizzled 16B slots
    __shared__ float lsum[GNUM], lsq[GNUM];

    const int tid  = threadIdx.x;
    const int lane = tid & 63;
    const int wv   = tid >> 6;             // 0..3
    // XCD-chunked bijective swizzle (1024 = 8 * 128)
    const int bid  = ((int)blockIdx.x & 7) * 128 + ((int)blockIdx.x >> 3);
    const int q    = bid & 3;              // out quarter
    const int pt   = (bid >> 2) & 63;      // pixel tile
    const int b    = bid >> 8;             // batch
    const int pix0 = pt << 6;
    const int out  = q * 64 + wv * 16 + (lane & 15);
    const int q8   = lane >> 4;            // k8-block 0..3

    if (tid < GNUM) { lsum[tid] = 0.f; lsq[tid] = 0.f; }

    f32x4 acc[4];
#pragma unroll
    for (int i = 0; i < 4; ++i) acc[i] = (f32x4)0.f;

    const ushort* srow = Sg + ((size_t)(b * NCH) * HW + pix0) * 64;
    short8 st0, st1;                       // stage registers (8KB = 2 x 16B/thr)

    auto stage_load = [&](int ch) {
        const ushort* src = srow + (size_t)ch * HW * 64 + tid * 8;
        st0 = *reinterpret_cast<const short8*>(src);
        st1 = *reinterpret_cast<const short8*>(src + 2048);
    };
    auto stage_write = [&](int buf) {
        *reinterpret_cast<short8*>(&Sm[buf][tid * 8])        = st0;
        *reinterpret_cast<short8*>(&Sm[buf][tid * 8 + 2048]) = st1;
    };

    // prologue: chunk 0 into buf 0
    stage_load(0);
    stage_write(0);
    __syncthreads();

    for (int ch = 0; ch < NCH; ++ch) {
        // B-frags for this chunk FIRST (oldest in vmcnt queue)
        short8 b0 = *reinterpret_cast<const short8*>(
            wB + ((size_t)((ch*2+0) * 256 + out) * 32 + q8 * 8));
        short8 b1 = *reinterpret_cast<const short8*>(
            wB + ((size_t)((ch*2+1) * 256 + out) * 32 + q8 * 8));
        if (ch + 1 < NCH) stage_load(ch + 1);   // stays in flight during MFMA

        const ushort* Sb = Sm[ch & 1];
#pragma unroll
        for (int mt = 0; mt < 4; ++mt) {
            int pixL = mt * 16 + (lane & 15);
            short8 a0 = *reinterpret_cast<const short8*>(
                &Sb[pixL * 64 + ((q8) ^ (pixL & 7)) * 8]);
            short8 a1 = *reinterpret_cast<const short8*>(
                &Sb[pixL * 64 + ((4 + q8) ^ (pixL & 7)) * 8]);
            acc[mt] = __builtin_amdgcn_mfma_f32_16x16x32_bf16(a0, b0, acc[mt], 0, 0, 0);
            acc[mt] = __builtin_amdgcn_mfma_f32_16x16x32_bf16(a1, b1, acc[mt], 0, 0, 0);
        }

        if (ch + 1 < NCH) stage_write((ch + 1) & 1);   // drains stage loads here
        __syncthreads();
    }

    // ---- epilogue: write y, accumulate GN stats ----  [r8-verified form]
    float s_ = 0.f, q_ = 0.f;
#pragma unroll
    for (int mt = 0; mt < 4; ++mt) {
        float4 st;
        st.x = acc[mt][0]; st.y = acc[mt][1];
        st.z = acc[mt][2]; st.w = acc[mt][3];
        s_ += st.x + st.y + st.z + st.w;
        q_ += st.x*st.x + st.y*st.y + st.z*st.z + st.w*st.w;
        float* yr = y + (size_t)(b * COUT + out) * HW
                      + pix0 + mt * 16 + (lane >> 4) * 4;
        *reinterpret_cast<float4*>(yr) = st;
    }
    atomicAdd(&lsum[out >> 3], s_);
    atomicAdd(&lsq [out >> 3], q_);
    __syncthreads();
    if (tid < GNUM) {
        float ls = lsum[tid], lq = lsq[tid];
        if (ls != 0.f || lq != 0.f) {          // only groups this block touched
            atomicAdd(&gsum[b * GNUM + tid], ls);
            atomicAdd(&gsq [b * GNUM + tid], lq);
        }
    }
}

// ---------------------------------------------------------------------------
// Kernel 5: finalize GN statistics (128 groups)   [verified]
__global__ void stats_kernel(const float* __restrict__ gsum,
                             const float* __restrict__ gsq,
                             float* __restrict__ mean,
                             float* __restrict__ rstd) {
    int t = threadIdx.x;
    if (t < BATCH * GNUM) {
        float m = gsum[t] * (1.f / GN_N);
        float v = gsq[t] * (1.f / GN_N) - m * m;
        mean[t] = m;
        rstd[t] = rsqrtf(v + 1e-5f);
    }
}

// ---------------------------------------------------------------------------
// Kernel 6: apply GN affine + ReLU (float4, memory-bound)   [verified]
__global__ void apply_kernel(const float* __restrict__ y,
                             const float* __restrict__ mean,
                             const float* __restrict__ rstd,
                             const float* __restrict__ gamma,
                             const float* __restrict__ beta,
                             float* __restrict__ out) {
    int i = blockIdx.x * 256 + threadIdx.x;        // float4 index
    if (i >= (BATCH * COUT * HW) / 4) return;
    float4 v = ((const float4*)y)[i];
    int idx = i * 4;
    int b = idx >> 20;
    int c = (idx >> 12) & 255;
    int gi = b * GNUM + (c >> 3);
    float r = rstd[gi];
    float g = gamma[c] * r;
    float be = beta[c] - mean[gi] * g;
    float4 o;
    o.x = fmaxf(v.x * g + be, 0.f);
    o.y = fmaxf(v.y * g + be, 0.f);
    o.z = fmaxf(v.z * g + be, 0.f);
    o.w = fmaxf(v.w * g + be, 0.f);
    ((float4*)out)[i] = o;
}

// ---------------------------------------------------------------------------
extern "C" void kernel_launch(void* const* d_in, const int* in_sizes, int n_in,
                              void* d_out, int out_size, void* d_ws, size_t ws_size,
                              hipStream_t stream) {
    const float* x     = (const float*)d_in[0];
    const float* shp   = (const float*)d_in[1];
    const float* wo    = (const float*)d_in[2];
    const float* wd    = (const float*)d_in[3];
    const float* gamma = (const float*)d_in[4];
    const float* beta  = (const float*)d_in[5];
    float* out = (float*)d_out;
    float* ws  = (float*)d_ws;

    float4* coeff = (float4*)(ws + OFF_COEFF);
    ushort* wB    = (ushort*)(ws + OFF_WB);
    ushort* Sg    = (ushort*)(ws + OFF_S);
    float*  y     = ws + OFF_Y;
    float*  gsum  = ws + OFF_GSUM;
    float*  gsq   = ws + OFF_GSQ;
    float*  mean  = ws + OFF_MEAN;
    float*  rstd  = ws + OFF_RSTD;

    // zero GN accumulators (gsum+gsq contiguous, 256 floats)
    hipMemsetAsync(gsum, 0, 256 * sizeof(float), stream);

    offs_kernel<<<dim3((BATCH*NCH*HW + 255) / 256), dim3(256), 0, stream>>>(shp, wo, coeff);
    wb_kernel<<<dim3((NKSTEP*COUT*32 + 255) / 256), dim3(256), 0, stream>>>(wd, wB);
    sample_kernel<<<dim3(BATCH*NCH*128), dim3(256), 0, stream>>>(x, coeff, Sg);
    gemm_kernel<<<dim3(1024), dim3(256), 0, stream>>>(Sg, wB, y, gsum, gsq);
    stats_kernel<<<dim3(1), dim3(128), 0, stream>>>(gsum, gsq, mean, rstd);
    apply_kernel<<<dim3((BATCH*COUT*HW/4 + 255) / 256), dim3(256), 0, stream>>>(
        y, mean, rstd, gamma, beta, out);
}